// Round 7
// baseline (517.392 us; speedup 1.0000x reference)
//
#include <hip/hip_runtime.h>

#define NG     64
#define N1i    65
#define BPTS   262144
#define NBIN   8192          // 4096 Morton buckets x 2 z-halves
#define BINCAP 88            // per-bin capacity: mean 32, ~10 sigma margin
#define NCORN  75            // 5x5x3 corner vectors per half-bucket
#define SMEM_VEC (NCORN * 64) // 4800 float4 = 76800 B -> 2 blocks/CU

__device__ __forceinline__ int morton12(int bx, int by, int bz) {
    int m = 0;
#pragma unroll
    for (int i = 0; i < 4; ++i) {
        m |= ((bx >> i) & 1) << (3 * i + 2);
        m |= ((by >> i) & 1) << (3 * i + 1);
        m |= ((bz >> i) & 1) << (3 * i + 0);
    }
    return m;
}

// K1: bin points into fixed-capacity slots. One kernel, device atomics
// (rounds 0/1/4 proved atomic cost is NOT the aux bottleneck).
__global__ __launch_bounds__(256) void binscatter_kernel(
    const float* __restrict__ x, int* __restrict__ cnt, int* __restrict__ slots)
{
    const int p = blockIdx.x * 256 + threadIdx.x;
    const float rx = (x[3 * p + 0] + 1.0f) * 32.0f;
    const float ry = (x[3 * p + 1] + 1.0f) * 32.0f;
    const float rz = (x[3 * p + 2] + 1.0f) * 32.0f;
    const int ix = min(max((int)floorf(rx), 0), NG - 1);
    const int iy = min(max((int)floorf(ry), 0), NG - 1);
    const int iz = min(max((int)floorf(rz), 0), NG - 1);
    const int bin = morton12(ix >> 2, iy >> 2, iz >> 2) * 2 + ((iz >> 1) & 1);
    const int pos = atomicAdd(&cnt[bin], 1);
    if (pos < BINCAP) slots[bin * BINCAP + pos] = p;
}

// K2: one 1024-thread block per half-bucket; stage 5x5x3 corner region
// (76.8 KB -> 2 blocks/CU), serve all 8 per-point corner gathers from LDS.
// Stores are PLAIN (write-back through L2): the nt variant bypassed L2 and
// capped the kernel at ~1.4 TB/s of scattered HBM writes (rounds 1-6 invariant).
__global__ __launch_bounds__(1024) void trilerp_kernel(
    const float*  __restrict__ x,
    const float*  __restrict__ gv,
    const float4* __restrict__ gf,
    const int*    __restrict__ cnt,
    const int*    __restrict__ slots,
    float*        __restrict__ outv,
    float4*       __restrict__ outf)
{
    extern __shared__ float4 smem4[];             // 4800 float4 = 76800 B
    float* smem_gv = (float*)&smem4[SMEM_VEC];    // 75 floats

    const int tid = threadIdx.x;
    // XCD-chunked swizzle: consecutive (Morton-adjacent) bins -> same XCD L2.
    const int bin    = (blockIdx.x & 7) * (NBIN / 8) + (blockIdx.x >> 3);
    const int bucket = bin >> 1;
    const int half   = bin & 1;
    int bx = 0, by = 0, bz = 0;
#pragma unroll
    for (int i = 0; i < 4; ++i) {
        bx |= ((bucket >> (3 * i + 2)) & 1) << i;
        by |= ((bucket >> (3 * i + 1)) & 1) << i;
        bz |= ((bucket >> (3 * i + 0)) & 1) << i;
    }
    const int gx0 = bx * 4, gy0 = by * 4, gz0 = bz * 4 + half * 2;

    // ---- stage: 75 corner vectors (each 64 float4, wave-coalesced 1KB) ----
    for (int i = tid; i < SMEM_VEC; i += 1024) {
        const int c = i >> 6, f = i & 63;
        const int cz = c % 3, cyx = c / 3;
        const int cy = cyx % 5, cx = cyx / 5;
        const int gidx = ((gx0 + cx) * N1i + (gy0 + cy)) * N1i + (gz0 + cz);
        smem4[i] = gf[(size_t)gidx * 64 + f];
    }
    if (tid < NCORN) {
        const int cz = tid % 3, cyx = tid / 3;
        const int cy = cyx % 5, cx = cyx / 5;
        smem_gv[tid] = gv[((gx0 + cx) * N1i + (gy0 + cy)) * N1i + (gz0 + cz)];
    }
    const int n = min(cnt[bin], BINCAP);
    __syncthreads();

    const int lane = tid & 63;
    const int wid  = tid >> 6;                 // 0..15

    for (int k = wid; k < n; k += 16) {
        const int p = slots[bin * BINCAP + k];

        const float rx = (x[3 * p + 0] + 1.0f) * 32.0f;
        const float ry = (x[3 * p + 1] + 1.0f) * 32.0f;
        const float rz = (x[3 * p + 2] + 1.0f) * 32.0f;

        const bool valid = (rx >= 0.0f) & (rx <= 64.0f) &
                           (ry >= 0.0f) & (ry <= 64.0f) &
                           (rz >= 0.0f) & (rz <= 64.0f);

        int ix = min(max((int)floorf(rx), 0), NG - 1);
        int iy = min(max((int)floorf(ry), 0), NG - 1);
        int iz = min(max((int)floorf(rz), 0), NG - 1);

        const float tx = rx - (float)ix;
        const float ty = ry - (float)iy;
        const float tz = rz - (float)iz;

        const int lx = ix - gx0, ly = iy - gy0, lz = iz - gz0;  // lz in 0..1
        const int c0 = (lx * 5 + ly) * 3 + lz;

        const float wx0 = 1.0f - tx, wy0 = 1.0f - ty, wz0 = 1.0f - tz;
        float w[8];
        w[0] = wx0 * wy0 * wz0;
        w[1] = wx0 * wy0 * tz;
        w[2] = wx0 * ty  * wz0;
        w[3] = wx0 * ty  * tz;
        w[4] = tx  * wy0 * wz0;
        w[5] = tx  * wy0 * tz;
        w[6] = tx  * ty  * wz0;
        w[7] = tx  * ty  * tz;

        const int off[8] = {0, 1, 3, 4, 15, 16, 18, 19};

        float4 acc = make_float4(0.f, 0.f, 0.f, 0.f);
#pragma unroll
        for (int c = 0; c < 8; ++c) {
            const float4 v = smem4[(c0 + off[c]) * 64 + lane];
            acc.x += w[c] * v.x;
            acc.y += w[c] * v.y;
            acc.z += w[c] * v.z;
            acc.w += w[c] * v.w;
        }
        if (!valid) acc = make_float4(0.f, 0.f, 0.f, 0.f);
        outf[(size_t)p * 64 + lane] = acc;     // plain store: drain via L2

        float s = 0.0f;                        // wave-uniform (LDS broadcast)
#pragma unroll
        for (int c = 0; c < 8; ++c) s += w[c] * smem_gv[c0 + off[c]];
        if (lane == 0)
            outv[p] = valid ? s : 0.0f;        // plain store
    }
}

extern "C" void kernel_launch(void* const* d_in, const int* in_sizes, int n_in,
                              void* d_out, int out_size, void* d_ws, size_t ws_size,
                              hipStream_t stream) {
    const float*  x  = (const float*)d_in[0];
    const float*  gv = (const float*)d_in[1];
    const float4* gf = (const float4*)d_in[2];

    float*  outv = (float*)d_out;                    // (B,1)
    float4* outf = (float4*)((float*)d_out + BPTS);  // (B,256)

    // workspace: [cnt: NBIN ints (32 KB)][slots: NBIN*BINCAP ints (2.88 MB)]
    int* cnt   = (int*)d_ws;
    int* slots = cnt + NBIN;

    hipMemsetAsync(cnt, 0, NBIN * sizeof(int), stream);
    binscatter_kernel<<<BPTS / 256, 256, 0, stream>>>(x, cnt, slots);

    const size_t smem_bytes = SMEM_VEC * sizeof(float4) + NCORN * sizeof(float);
    trilerp_kernel<<<NBIN, 1024, smem_bytes, stream>>>(x, gv, gf, cnt, slots, outv, outf);
}

// Round 9
// 512.938 us; speedup vs baseline: 1.0087x; 1.0087x over previous
//
#include <hip/hip_runtime.h>

#define NG     64
#define N1i    65
#define BPTS   262144
#define NBIN   8192          // 4096 Morton buckets x 2 z-halves
#define BINCAP 88            // per-bin capacity: mean 32, ~10 sigma margin
#define NCORN  75            // 5x5x3 corner vectors per half-bucket
#define SMEM_VEC (NCORN * 64) // 4800 float4 = 76800 B -> 2 blocks/CU

__device__ __forceinline__ int morton12(int bx, int by, int bz) {
    int m = 0;
#pragma unroll
    for (int i = 0; i < 4; ++i) {
        m |= ((bx >> i) & 1) << (3 * i + 2);
        m |= ((by >> i) & 1) << (3 * i + 1);
        m |= ((bz >> i) & 1) << (3 * i + 0);
    }
    return m;
}

// K1: bin points into fixed-capacity slots.
__global__ __launch_bounds__(256) void binscatter_kernel(
    const float* __restrict__ x, int* __restrict__ cnt, int* __restrict__ slots)
{
    const int p = blockIdx.x * 256 + threadIdx.x;
    const float rx = (x[3 * p + 0] + 1.0f) * 32.0f;
    const float ry = (x[3 * p + 1] + 1.0f) * 32.0f;
    const float rz = (x[3 * p + 2] + 1.0f) * 32.0f;
    const int ix = min(max((int)floorf(rx), 0), NG - 1);
    const int iy = min(max((int)floorf(ry), 0), NG - 1);
    const int iz = min(max((int)floorf(rz), 0), NG - 1);
    const int bin = morton12(ix >> 2, iy >> 2, iz >> 2) * 2 + ((iz >> 1) & 1);
    const int pos = atomicAdd(&cnt[bin], 1);
    if (pos < BINCAP) slots[bin * BINCAP + pos] = p;
}

// Per-point compute+store, fed with pre-loaded coordinates.
__device__ __forceinline__ void compute_store(
    const float4* __restrict__ smem4, const float* __restrict__ smem_gv,
    float px, float py, float pz, int p,
    int gx0, int gy0, int gz0, int lane,
    float* __restrict__ outv, float4* __restrict__ outf)
{
    const float rx = (px + 1.0f) * 32.0f;
    const float ry = (py + 1.0f) * 32.0f;
    const float rz = (pz + 1.0f) * 32.0f;

    const bool valid = (rx >= 0.0f) & (rx <= 64.0f) &
                       (ry >= 0.0f) & (ry <= 64.0f) &
                       (rz >= 0.0f) & (rz <= 64.0f);

    int ix = min(max((int)floorf(rx), 0), NG - 1);
    int iy = min(max((int)floorf(ry), 0), NG - 1);
    int iz = min(max((int)floorf(rz), 0), NG - 1);

    const float tx = rx - (float)ix;
    const float ty = ry - (float)iy;
    const float tz = rz - (float)iz;

    const int lx = ix - gx0, ly = iy - gy0, lz = iz - gz0;  // lz in 0..1
    const int c0 = (lx * 5 + ly) * 3 + lz;

    const float wx0 = 1.0f - tx, wy0 = 1.0f - ty, wz0 = 1.0f - tz;
    float w[8];
    w[0] = wx0 * wy0 * wz0;
    w[1] = wx0 * wy0 * tz;
    w[2] = wx0 * ty  * wz0;
    w[3] = wx0 * ty  * tz;
    w[4] = tx  * wy0 * wz0;
    w[5] = tx  * wy0 * tz;
    w[6] = tx  * ty  * wz0;
    w[7] = tx  * ty  * tz;

    const int off[8] = {0, 1, 3, 4, 15, 16, 18, 19};

    float4 acc = make_float4(0.f, 0.f, 0.f, 0.f);
#pragma unroll
    for (int c = 0; c < 8; ++c) {
        const float4 v = smem4[(c0 + off[c]) * 64 + lane];
        acc.x += w[c] * v.x;
        acc.y += w[c] * v.y;
        acc.z += w[c] * v.z;
        acc.w += w[c] * v.w;
    }
    if (!valid) acc = make_float4(0.f, 0.f, 0.f, 0.f);
    outf[(size_t)p * 64 + lane] = acc;

    if (lane == 0) {                          // gv path: 1 lane, not 64-wide broadcast
        float s = 0.0f;
#pragma unroll
        for (int c = 0; c < 8; ++c) s += w[c] * smem_gv[c0 + off[c]];
        outv[p] = valid ? s : 0.0f;
    }
}

// K2: one block per half-bucket; 5x5x3 corner region staged in LDS (76.8 KB,
// 2 blocks/CU). Inner loop: 2-deep point pipeline — both points' global loads
// issue before either point's compute/stores, doubling in-flight memory per
// wave (tests the latency/store-serialization theory vs the write-BW-cap theory).
__global__ __launch_bounds__(1024, 8) void trilerp_kernel(
    const float*  __restrict__ x,
    const float*  __restrict__ gv,
    const float4* __restrict__ gf,
    const int*    __restrict__ cnt,
    const int*    __restrict__ slots,
    float*        __restrict__ outv,
    float4*       __restrict__ outf)
{
    extern __shared__ float4 smem4[];             // 4800 float4 = 76800 B
    float* smem_gv = (float*)&smem4[SMEM_VEC];    // 75 floats

    const int tid = threadIdx.x;
    // XCD-chunked swizzle: Morton-adjacent bins -> same XCD L2.
    const int bin    = (blockIdx.x & 7) * (NBIN / 8) + (blockIdx.x >> 3);
    const int bucket = bin >> 1;
    const int half   = bin & 1;
    int bx = 0, by = 0, bz = 0;
#pragma unroll
    for (int i = 0; i < 4; ++i) {
        bx |= ((bucket >> (3 * i + 2)) & 1) << i;
        by |= ((bucket >> (3 * i + 1)) & 1) << i;
        bz |= ((bucket >> (3 * i + 0)) & 1) << i;
    }
    const int gx0 = bx * 4, gy0 = by * 4, gz0 = bz * 4 + half * 2;

    // ---- stage: 75 corner vectors (each 64 float4, wave-coalesced 1KB) ----
    for (int i = tid; i < SMEM_VEC; i += 1024) {
        const int c = i >> 6, f = i & 63;
        const int cz = c % 3, cyx = c / 3;
        const int cy = cyx % 5, cx = cyx / 5;
        const int gidx = ((gx0 + cx) * N1i + (gy0 + cy)) * N1i + (gz0 + cz);
        smem4[i] = gf[(size_t)gidx * 64 + f];
    }
    if (tid < NCORN) {
        const int cz = tid % 3, cyx = tid / 3;
        const int cy = cyx % 5, cx = cyx / 5;
        smem_gv[tid] = gv[((gx0 + cx) * N1i + (gy0 + cy)) * N1i + (gz0 + cz)];
    }
    const int n = min(cnt[bin], BINCAP);
    __syncthreads();

    const int lane = tid & 63;
    const int wid  = tid >> 6;                 // 0..15
    const int binbase = bin * BINCAP;

    int k = wid;
    // paired iterations: issue BOTH points' slot+x loads before any compute
    for (; k + 16 < n; k += 32) {
        const int pa = slots[binbase + k];
        const int pb = slots[binbase + k + 16];
        const float xa0 = x[3 * pa + 0], xa1 = x[3 * pa + 1], xa2 = x[3 * pa + 2];
        const float xb0 = x[3 * pb + 0], xb1 = x[3 * pb + 1], xb2 = x[3 * pb + 2];
        compute_store(smem4, smem_gv, xa0, xa1, xa2, pa, gx0, gy0, gz0, lane, outv, outf);
        compute_store(smem4, smem_gv, xb0, xb1, xb2, pb, gx0, gy0, gz0, lane, outv, outf);
    }
    if (k < n) {
        const int pa = slots[binbase + k];
        const float xa0 = x[3 * pa + 0], xa1 = x[3 * pa + 1], xa2 = x[3 * pa + 2];
        compute_store(smem4, smem_gv, xa0, xa1, xa2, pa, gx0, gy0, gz0, lane, outv, outf);
    }
}

extern "C" void kernel_launch(void* const* d_in, const int* in_sizes, int n_in,
                              void* d_out, int out_size, void* d_ws, size_t ws_size,
                              hipStream_t stream) {
    const float*  x  = (const float*)d_in[0];
    const float*  gv = (const float*)d_in[1];
    const float4* gf = (const float4*)d_in[2];

    float*  outv = (float*)d_out;                    // (B,1)
    float4* outf = (float4*)((float*)d_out + BPTS);  // (B,256)

    // workspace: [cnt: NBIN ints (32 KB)][slots: NBIN*BINCAP ints (2.88 MB)]
    int* cnt   = (int*)d_ws;
    int* slots = cnt + NBIN;

    hipMemsetAsync(cnt, 0, NBIN * sizeof(int), stream);
    binscatter_kernel<<<BPTS / 256, 256, 0, stream>>>(x, cnt, slots);

    const size_t smem_bytes = SMEM_VEC * sizeof(float4) + NCORN * sizeof(float);
    trilerp_kernel<<<NBIN, 1024, smem_bytes, stream>>>(x, gv, gf, cnt, slots, outv, outf);
}

// Round 12
// 510.885 us; speedup vs baseline: 1.0127x; 1.0040x over previous
//
#include <hip/hip_runtime.h>

#define NG     64
#define N1i    65
#define BPTS   262144
#define NBIN   8192          // 4096 Morton buckets x 2 z-halves
#define BINCAP 88            // per-bin capacity: mean 32, ~10 sigma margin
#define NCORN  75            // 5x5x3 corner vectors per half-bucket
#define SMEM_VEC (NCORN * 64) // 4800 float4 = 76800 B; total LDS 78.5 KB -> 2 blocks/CU

__device__ __forceinline__ int morton12(int bx, int by, int bz) {
    int m = 0;
#pragma unroll
    for (int i = 0; i < 4; ++i) {
        m |= ((bx >> i) & 1) << (3 * i + 2);
        m |= ((by >> i) & 1) << (3 * i + 1);
        m |= ((bz >> i) & 1) << (3 * i + 0);
    }
    return m;
}

// K1: bin points into fixed-capacity slots.
__global__ __launch_bounds__(256) void binscatter_kernel(
    const float* __restrict__ x, int* __restrict__ cnt, int* __restrict__ slots)
{
    const int p = blockIdx.x * 256 + threadIdx.x;
    const float rx = (x[3 * p + 0] + 1.0f) * 32.0f;
    const float ry = (x[3 * p + 1] + 1.0f) * 32.0f;
    const float rz = (x[3 * p + 2] + 1.0f) * 32.0f;
    const int ix = min(max((int)floorf(rx), 0), NG - 1);
    const int iy = min(max((int)floorf(ry), 0), NG - 1);
    const int iz = min(max((int)floorf(rz), 0), NG - 1);
    const int bin = morton12(ix >> 2, iy >> 2, iz >> 2) * 2 + ((iz >> 1) & 1);
    const int pos = atomicAdd(&cnt[bin], 1);
    if (pos < BINCAP) slots[bin * BINCAP + pos] = p;
}

// K2: one block per half-bucket. ALL global reads (gf region, gv region,
// slots, x coords) happen in one staging burst; the point loop then issues
// ONLY LDS reads + global stores. This bunches reads away from writes to
// minimize HBM bus read/write turnaround (the theory for the 1.5 TB/s write
// cap observed across rounds 6-9).
__global__ __launch_bounds__(1024, 8) void trilerp_kernel(
    const float*  __restrict__ x,
    const float*  __restrict__ gv,
    const float4* __restrict__ gf,
    const int*    __restrict__ cnt,
    const int*    __restrict__ slots,
    float*        __restrict__ outv,
    float4*       __restrict__ outf)
{
    extern __shared__ float4 smem4[];             // 4800 float4 = 76800 B
    float* smem_gv = (float*)&smem4[SMEM_VEC];    // 75 floats
    int*   s_slot  = (int*)(smem_gv + 80);        // BINCAP ints
    float* s_x     = (float*)(s_slot + BINCAP);   // BINCAP*3 floats

    const int tid = threadIdx.x;
    // XCD-chunked swizzle: Morton-adjacent bins -> same XCD L2.
    const int bin    = (blockIdx.x & 7) * (NBIN / 8) + (blockIdx.x >> 3);
    const int bucket = bin >> 1;
    const int half   = bin & 1;
    int bx = 0, by = 0, bz = 0;
#pragma unroll
    for (int i = 0; i < 4; ++i) {
        bx |= ((bucket >> (3 * i + 2)) & 1) << i;
        by |= ((bucket >> (3 * i + 1)) & 1) << i;
        bz |= ((bucket >> (3 * i + 0)) & 1) << i;
    }
    const int gx0 = bx * 4, gy0 = by * 4, gz0 = bz * 4 + half * 2;

    const int n = min(cnt[bin], BINCAP);
    const int binbase = bin * BINCAP;

    // ---- staging burst: gf region + gv region + slots + x, all at once ----
    for (int i = tid; i < SMEM_VEC; i += 1024) {
        const int c = i >> 6, f = i & 63;
        const int cz = c % 3, cyx = c / 3;
        const int cy = cyx % 5, cx = cyx / 5;
        const int gidx = ((gx0 + cx) * N1i + (gy0 + cy)) * N1i + (gz0 + cz);
        smem4[i] = gf[(size_t)gidx * 64 + f];
    }
    if (tid < NCORN) {
        const int cz = tid % 3, cyx = tid / 3;
        const int cy = cyx % 5, cx = cyx / 5;
        smem_gv[tid] = gv[((gx0 + cx) * N1i + (gy0 + cy)) * N1i + (gz0 + cz)];
    }
    if (tid < n) {
        const int p = slots[binbase + tid];
        s_slot[tid] = p;
        s_x[3 * tid + 0] = x[3 * p + 0];
        s_x[3 * tid + 1] = x[3 * p + 1];
        s_x[3 * tid + 2] = x[3 * p + 2];
    }
    __syncthreads();

    const int lane = tid & 63;
    const int wid  = tid >> 6;                 // 0..15

    // ---- point loop: LDS reads + global STORES only ----
    for (int k = wid; k < n; k += 16) {
        const int p = s_slot[k];
        const float rx = (s_x[3 * k + 0] + 1.0f) * 32.0f;
        const float ry = (s_x[3 * k + 1] + 1.0f) * 32.0f;
        const float rz = (s_x[3 * k + 2] + 1.0f) * 32.0f;

        const bool valid = (rx >= 0.0f) & (rx <= 64.0f) &
                           (ry >= 0.0f) & (ry <= 64.0f) &
                           (rz >= 0.0f) & (rz <= 64.0f);

        int ix = min(max((int)floorf(rx), 0), NG - 1);
        int iy = min(max((int)floorf(ry), 0), NG - 1);
        int iz = min(max((int)floorf(rz), 0), NG - 1);

        const float tx = rx - (float)ix;
        const float ty = ry - (float)iy;
        const float tz = rz - (float)iz;

        const int lx = ix - gx0, ly = iy - gy0, lz = iz - gz0;  // lz in 0..1
        const int c0 = (lx * 5 + ly) * 3 + lz;

        const float wx0 = 1.0f - tx, wy0 = 1.0f - ty, wz0 = 1.0f - tz;
        float w[8];
        w[0] = wx0 * wy0 * wz0;
        w[1] = wx0 * wy0 * tz;
        w[2] = wx0 * ty  * wz0;
        w[3] = wx0 * ty  * tz;
        w[4] = tx  * wy0 * wz0;
        w[5] = tx  * wy0 * tz;
        w[6] = tx  * ty  * wz0;
        w[7] = tx  * ty  * tz;

        const int off[8] = {0, 1, 3, 4, 15, 16, 18, 19};

        float4 acc = make_float4(0.f, 0.f, 0.f, 0.f);
#pragma unroll
        for (int c = 0; c < 8; ++c) {
            const float4 v = smem4[(c0 + off[c]) * 64 + lane];
            acc.x += w[c] * v.x;
            acc.y += w[c] * v.y;
            acc.z += w[c] * v.z;
            acc.w += w[c] * v.w;
        }
        if (!valid) acc = make_float4(0.f, 0.f, 0.f, 0.f);
        outf[(size_t)p * 64 + lane] = acc;

        if (lane == 0) {
            float s = 0.0f;
#pragma unroll
            for (int c = 0; c < 8; ++c) s += w[c] * smem_gv[c0 + off[c]];
            outv[p] = valid ? s : 0.0f;
        }
    }
}

extern "C" void kernel_launch(void* const* d_in, const int* in_sizes, int n_in,
                              void* d_out, int out_size, void* d_ws, size_t ws_size,
                              hipStream_t stream) {
    const float*  x  = (const float*)d_in[0];
    const float*  gv = (const float*)d_in[1];
    const float4* gf = (const float4*)d_in[2];

    float*  outv = (float*)d_out;                    // (B,1)
    float4* outf = (float4*)((float*)d_out + BPTS);  // (B,256)

    // workspace: [cnt: NBIN ints (32 KB)][slots: NBIN*BINCAP ints (2.88 MB)]
    int* cnt   = (int*)d_ws;
    int* slots = cnt + NBIN;

    hipMemsetAsync(cnt, 0, NBIN * sizeof(int), stream);
    binscatter_kernel<<<BPTS / 256, 256, 0, stream>>>(x, cnt, slots);

    const size_t smem_bytes = SMEM_VEC * sizeof(float4) + 80 * sizeof(float)
                            + BINCAP * sizeof(int) + BINCAP * 3 * sizeof(float);
    trilerp_kernel<<<NBIN, 1024, smem_bytes, stream>>>(x, gv, gf, cnt, slots, outv, outf);
}